// Round 1
// baseline (477.709 us; speedup 1.0000x reference)
//
#include <hip/hip_runtime.h>

#define HH 384
#define WW2 384
#define HWS (HH*WW2)
#define NB 8
#define EPSV 1e-4f

// ---------------- color transform: xg = gcm @ x ----------------
__global__ __launch_bounds__(256) void k_colortx(const float* __restrict__ x,
                                                 const float* __restrict__ gcm,
                                                 float* __restrict__ xg) {
  int i = blockIdx.x * 256 + threadIdx.x;
  if (i >= NB * HWS) return;
  int b = i / HWS, p = i % HWS;
  const float* xb = x + (size_t)b * 3 * HWS + p;
  float x0 = xb[0], x1 = xb[HWS], x2 = xb[2 * HWS];
  float* o = xg + (size_t)b * 3 * HWS + p;
  o[0]       = gcm[0] * x0 + gcm[1] * x1 + gcm[2] * x2;
  o[HWS]     = gcm[3] * x0 + gcm[4] * x1 + gcm[5] * x2;
  o[2 * HWS] = gcm[6] * x0 + gcm[7] * x1 + gcm[8] * x2;
}

// ---------------- coefficient folding for the final 1x1 convs ----------------
__global__ void k_coef(const float* __restrict__ adj_w,   // (64,64)
                       const float* __restrict__ convH_w, const float* __restrict__ convH_b,
                       const float* __restrict__ convS_w, const float* __restrict__ convS_b,
                       const float* __restrict__ convRGB_w, const float* __restrict__ convRGB_b,
                       float* __restrict__ coef /* 64 x 8 */) {
  int o = threadIdx.x;
  if (o >= 64) return;
  const float* a = adj_w + o * 64;
  float aH = 0, bH = 0, aS = 0, bS = 0, aR0 = 0, aR1 = 0, aR2 = 0, bR = 0;
  for (int i = 0; i < 16; i++) {
    aH += a[i] * convH_w[i];
    bH += a[i] * convH_b[i];
    aS += a[16 + i] * convS_w[i];
    bS += a[16 + i] * convS_b[i];
    float w = a[32 + i];
    aR0 += w * convRGB_w[i * 3 + 0];
    aR1 += w * convRGB_w[i * 3 + 1];
    aR2 += w * convRGB_w[i * 3 + 2];
    bR  += w * convRGB_b[i];
  }
  float* c = coef + o * 8;
  c[0] = aH; c[1] = bH; c[2] = aS; c[3] = bS;
  c[4] = aR0; c[5] = aR1; c[6] = aR2; c[7] = bR;
}

// ---------------- generic fused 3x3 conv ----------------
// block (16,16); each thread computes pixels (tx+{0,16}, ty+{0,16}) of a 32x32 tile.
// ACT: 0 none, 1 silu, 2 relu.  RED: COUT==1, block-reduce sum into partials.
template <int CIN, int COUT, int ACT, int RED>
__global__ __launch_bounds__(256) void k_conv3x3(const float* __restrict__ in,
                                                 const float* __restrict__ wgt,
                                                 const float* __restrict__ bias,
                                                 float* __restrict__ out,
                                                 float* __restrict__ partials) {
  constexpr int GC = (CIN < 4) ? CIN : 4;
  __shared__ float tile[GC][34][34];
  __shared__ float wl[CIN * 9 * COUT];  // [c][ky][kx][o]
  const int tid = threadIdx.y * 16 + threadIdx.x;
  const int b = blockIdx.z;
  const int bx = blockIdx.x * 32, by = blockIdx.y * 32;
  const float* inb = in + (size_t)b * CIN * HWS;

  for (int idx = tid; idx < COUT * CIN * 9; idx += 256) {
    int o = idx / (CIN * 9), r = idx % (CIN * 9);
    wl[r * COUT + o] = wgt[idx];
  }

  float acc[2][2][COUT];
#pragma unroll
  for (int dy = 0; dy < 2; dy++)
#pragma unroll
    for (int dx = 0; dx < 2; dx++)
#pragma unroll
      for (int o = 0; o < COUT; o++) acc[dy][dx][o] = bias[o];

  for (int cg = 0; cg < CIN; cg += GC) {
    __syncthreads();
    for (int idx = tid; idx < GC * 34 * 34; idx += 256) {
      int c = idx / (34 * 34), r = idx % (34 * 34);
      int yy = r / 34, xx = r % 34;
      int gy = by + yy - 1, gx = bx + xx - 1;
      float v = 0.f;
      if (gy >= 0 && gy < HH && gx >= 0 && gx < WW2)
        v = inb[(size_t)(cg + c) * HWS + (size_t)gy * WW2 + gx];
      tile[c][yy][xx] = v;
    }
    __syncthreads();
#pragma unroll
    for (int c = 0; c < GC; c++) {
#pragma unroll
      for (int ky = 0; ky < 3; ky++) {
#pragma unroll
        for (int kx = 0; kx < 3; kx++) {
          float v[2][2];
#pragma unroll
          for (int dy = 0; dy < 2; dy++)
#pragma unroll
            for (int dx = 0; dx < 2; dx++)
              v[dy][dx] = tile[c][threadIdx.y + dy * 16 + ky][threadIdx.x + dx * 16 + kx];
          const float* wr = &wl[(((cg + c) * 3 + ky) * 3 + kx) * COUT];
#pragma unroll
          for (int o = 0; o < COUT; o++) {
            float wv = wr[o];
#pragma unroll
            for (int dy = 0; dy < 2; dy++)
#pragma unroll
              for (int dx = 0; dx < 2; dx++)
                acc[dy][dx][o] = fmaf(v[dy][dx], wv, acc[dy][dx][o]);
          }
        }
      }
    }
  }

  if constexpr (RED) {
    float s = acc[0][0][0] + acc[0][1][0] + acc[1][0][0] + acc[1][1][0];
    __shared__ float red[256];
    __syncthreads();
    red[tid] = s;
    __syncthreads();
    for (int k = 128; k > 0; k >>= 1) {
      if (tid < k) red[tid] += red[tid + k];
      __syncthreads();
    }
    if (tid == 0)
      partials[(size_t)b * (gridDim.x * gridDim.y) + blockIdx.y * gridDim.x + blockIdx.x] = red[0];
    return;
  } else {
    (void)partials;
    float* ob = out + (size_t)b * COUT * HWS;
#pragma unroll
    for (int dy = 0; dy < 2; dy++)
#pragma unroll
      for (int dx = 0; dx < 2; dx++) {
        int gy = by + threadIdx.y + dy * 16;
        int gx = bx + threadIdx.x + dx * 16;
#pragma unroll
        for (int o = 0; o < COUT; o++) {
          float vv = acc[dy][dx][o];
          if (ACT == 1) vv = vv / (1.f + expf(-vv));
          else if (ACT == 2) vv = fmaxf(vv, 0.f);
          ob[(size_t)o * HWS + (size_t)gy * WW2 + gx] = vv;
        }
      }
  }
}

// ---------------- scale finalize + separable Gaussian taps ----------------
__global__ void k_scaletaps(const float* __restrict__ partials, float* __restrict__ taps) {
  int b = blockIdx.x, t = threadIdx.x;  // 64 threads
  __shared__ float red[64];
  float s = 0;
  for (int i = t; i < 144; i += 64) s += partials[(size_t)b * 144 + i];
  red[t] = s;
  __syncthreads();
  for (int k = 32; k > 0; k >>= 1) {
    if (t < k) red[t] += red[t + k];
    __syncthreads();
  }
  __shared__ float u[37];
  __shared__ float std_sh, f_sh;
  if (t == 0) {
    float mean = red[0] * (1.f / (float)HWS);
    float sc = fminf(2.5f, fmaxf(-2.5f, mean));
    std_sh = exp2f(sc);
    f_sh = ceilf(3.f * std_sh + 0.5f);
  }
  __syncthreads();
  if (t < 37) {
    float xv = (float)(t - 18);
    float q = xv / std_sh;
    u[t] = (fabsf(xv) <= f_sh) ? expf(-0.5f * q * q) : 0.f;
  }
  __syncthreads();
  if (t == 0) {
    float s1 = 0;
    for (int i = 0; i < 37; i++) s1 += u[i];
    float inv = 1.f / s1;
    for (int i = 0; i < 37; i++) taps[b * 37 + i] = u[i] * inv;
  }
}

// ---------------- separable 37-tap blur ----------------
__global__ __launch_bounds__(128) void k_blurH(const float* __restrict__ in,
                                               const float* __restrict__ taps,
                                               float* __restrict__ out) {
  __shared__ float row[128 + 36];
  __shared__ float tp[37];
  int img = blockIdx.z;          // b*3 + c
  int y = blockIdx.y;
  int x0 = blockIdx.x * 128;
  int t = threadIdx.x;
  const float* r = in + (size_t)img * HWS + (size_t)y * WW2;
  if (t < 37) tp[t] = taps[(img / 3) * 37 + t];
  for (int idx = t; idx < 128 + 36; idx += 128) {
    int gx = x0 + idx - 18;
    row[idx] = (gx >= 0 && gx < WW2) ? r[gx] : 0.f;
  }
  __syncthreads();
  float a = 0;
#pragma unroll
  for (int i = 0; i < 37; i++) a = fmaf(tp[i], row[t + i], a);
  out[(size_t)img * HWS + (size_t)y * WW2 + x0 + t] = a;
}

__global__ __launch_bounds__(128) void k_blurV(const float* __restrict__ in,
                                               const float* __restrict__ taps,
                                               float* __restrict__ out) {
  int img = blockIdx.z;
  int y = blockIdx.y;
  int x = blockIdx.x * 128 + threadIdx.x;
  __shared__ float tp[37];
  if (threadIdx.x < 37) tp[threadIdx.x] = taps[(img / 3) * 37 + threadIdx.x];
  __syncthreads();
  const float* base = in + (size_t)img * HWS;
  float a = 0;
#pragma unroll
  for (int i = 0; i < 37; i++) {
    int gy = y + i - 18;
    float v = (gy >= 0 && gy < HH) ? base[(size_t)gy * WW2 + x] : 0.f;
    a = fmaf(tp[i], v, a);
  }
  out[(size_t)img * HWS + (size_t)y * WW2 + x] = a;
}

// ---------------- final fusion ----------------
__global__ __launch_bounds__(256) void k_final(const float* __restrict__ x,
                                               const float* __restrict__ e3,
                                               const float* __restrict__ w2loc,
                                               const float* __restrict__ wp2_w,
                                               const float* __restrict__ wp2_b,
                                               const float* __restrict__ coef,
                                               const float* __restrict__ adj_b,
                                               float* __restrict__ out, int nb, int batch_base) {
  int i = blockIdx.x * 256 + threadIdx.x;
  if (i >= nb * HWS) return;
  int bl = i / HWS, p = i % HWS;
  int b = batch_base + bl;

  // RGB_order
  const float* xb = x + (size_t)b * 3 * HWS + p;
  float x0 = xb[0], x1 = xb[HWS], x2 = xb[2 * HWS];
  int mx = 0;  float vm = x0;
  if (x1 > vm) { mx = 1; vm = x1; }
  if (x2 > vm) { mx = 2; vm = x2; }
  int mxl = 0; vm = x0;
  if (x1 >= vm) { mxl = 1; vm = x1; }
  if (x2 >= vm) { mxl = 2; vm = x2; }
  int mn = 0;  float vn = x0;
  if (x1 < vn) { mn = 1; vn = x1; }
  if (x2 < vn) { mn = 2; vn = x2; }
  int mnl = 0; vn = x0;
  if (x1 <= vn) { mnl = 1; vn = x1; }
  if (x2 <= vn) { mnl = 2; vn = x2; }
  float R[3];
#pragma unroll
  for (int c = 0; c < 3; c++)
    R[c] = 0.5f * ((float)(c == mx) + (float)(c == mxl)) -
           0.5f * ((float)(c == mn) + (float)(c == mnl));

  // Hc / Sc
  const float* eb = e3 + (size_t)b * 3 * HWS + p;
  float E = eb[0], El = eb[HWS], Ell = eb[2 * HWS];
  float Hc = atanf(El / (Ell + EPSV));
  float Sc = logf((El * El + Ell * Ell) / (E * E + EPSV) + EPSV);

  // softmax weights from w2 (16 ch)
  const float* wb = w2loc + (size_t)bl * 16 * HWS + p;
  float lg[4];
#pragma unroll
  for (int j = 0; j < 4; j++) lg[j] = wp2_b[j];
#pragma unroll
  for (int c = 0; c < 16; c++) {
    float v = wb[(size_t)c * HWS];
#pragma unroll
    for (int j = 0; j < 4; j++) lg[j] = fmaf(v, wp2_w[j * 16 + c], lg[j]);
  }
  float m4 = fmaxf(fmaxf(lg[0], lg[1]), fmaxf(lg[2], lg[3]));
  float e0 = expf(lg[0] - m4), e1 = expf(lg[1] - m4), e2 = expf(lg[2] - m4), e3s = expf(lg[3] - m4);
  float inv = 1.f / (e0 + e1 + e2 + e3s);
  float w0 = e0 * inv, w1 = e1 * inv, w2s = e2 * inv;

  float t0 = Hc * w0, t1 = w0, t2 = Sc * w1, t3 = w1;
  float t4 = R[0] * w2s, t5 = R[1] * w2s, t6 = R[2] * w2s, t7 = w2s;

  float* ob = out + (size_t)b * 64 * HWS + p;
#pragma unroll
  for (int o = 0; o < 64; o++) {
    const float* cf = coef + o * 8;
    float v = adj_b[o];
    v = fmaf(cf[0], t0, v); v = fmaf(cf[1], t1, v);
    v = fmaf(cf[2], t2, v); v = fmaf(cf[3], t3, v);
    v = fmaf(cf[4], t4, v); v = fmaf(cf[5], t5, v);
    v = fmaf(cf[6], t6, v); v = fmaf(cf[7], t7, v);
    ob[(size_t)o * HWS] = v;
  }
}

// ---------------- host ----------------
extern "C" void kernel_launch(void* const* d_in, const int* in_sizes, int n_in,
                              void* d_out, int out_size, void* d_ws, size_t ws_size,
                              hipStream_t stream) {
  const float* x        = (const float*)d_in[0];
  const float* gcm      = (const float*)d_in[1];
  const float* convH_w  = (const float*)d_in[2];
  const float* convH_b  = (const float*)d_in[3];
  const float* convS_w  = (const float*)d_in[4];
  const float* convS_b  = (const float*)d_in[5];
  const float* convRGB_w= (const float*)d_in[6];
  const float* convRGB_b= (const float*)d_in[7];
  const float* convadj_w= (const float*)d_in[10];
  const float* convadj_b= (const float*)d_in[11];
  const float* c0_w = (const float*)d_in[12];
  const float* c0_b = (const float*)d_in[13];
  const float* c1_w = (const float*)d_in[14];
  const float* c1_b = (const float*)d_in[15];
  const float* c2_w = (const float*)d_in[16];
  const float* c2_b = (const float*)d_in[17];
  const float* wp0_w = (const float*)d_in[18];
  const float* wp0_b = (const float*)d_in[19];
  const float* wp1_w = (const float*)d_in[20];
  const float* wp1_b = (const float*)d_in[21];
  const float* wp2_w = (const float*)d_in[22];
  const float* wp2_b = (const float*)d_in[23];
  float* out = (float*)d_out;

  float* ws = (float*)d_ws;
  size_t off = 0;
  auto take = [&](size_t n) { float* p = ws + off; off += n; return p; };
  const size_t P3 = (size_t)NB * 3 * HWS;
  float* xg   = take(P3);
  float* tmp3 = take(P3);
  float* e3   = take(P3);
  float* partials = take(2048);
  float* taps = take(512);
  float* coef = take(1024);

  size_t avail = ws_size / sizeof(float);
  size_t remain = (avail > off) ? (avail - off) : 0;
  const size_t BIG_FULL = (size_t)NB * 16 * HWS;
  const size_t BIG_ONE  = (size_t)16 * HWS;
  bool full = remain >= 2 * BIG_FULL;
  float* bigA = take(full ? BIG_FULL : BIG_ONE);
  float* bigB = take(full ? BIG_FULL : BIG_ONE);

  dim3 cb(16, 16);
  k_colortx<<<(NB * HWS + 255) / 256, 256, 0, stream>>>(x, gcm, xg);
  k_coef<<<1, 64, 0, stream>>>(convadj_w, convH_w, convH_b, convS_w, convS_b,
                               convRGB_w, convRGB_b, coef);

  if (full) {
    k_conv3x3<3, 16, 1, 0><<<dim3(12, 12, NB), cb, 0, stream>>>(x, c0_w, c0_b, bigA, nullptr);
    k_conv3x3<16, 16, 1, 0><<<dim3(12, 12, NB), cb, 0, stream>>>(bigA, c1_w, c1_b, bigB, nullptr);
    k_conv3x3<16, 1, 0, 1><<<dim3(12, 12, NB), cb, 0, stream>>>(bigB, c2_w, c2_b, nullptr, partials);
  } else {
    for (int b = 0; b < NB; b++) {
      k_conv3x3<3, 16, 1, 0><<<dim3(12, 12, 1), cb, 0, stream>>>(x + (size_t)b * 3 * HWS, c0_w, c0_b, bigA, nullptr);
      k_conv3x3<16, 16, 1, 0><<<dim3(12, 12, 1), cb, 0, stream>>>(bigA, c1_w, c1_b, bigB, nullptr);
      k_conv3x3<16, 1, 0, 1><<<dim3(12, 12, 1), cb, 0, stream>>>(bigB, c2_w, c2_b, nullptr, partials + (size_t)b * 144);
    }
  }
  k_scaletaps<<<NB, 64, 0, stream>>>(partials, taps);
  k_blurH<<<dim3(3, HH, NB * 3), 128, 0, stream>>>(xg, taps, tmp3);
  k_blurV<<<dim3(3, HH, NB * 3), 128, 0, stream>>>(tmp3, taps, e3);

  if (full) {
    k_conv3x3<3, 16, 2, 0><<<dim3(12, 12, NB), cb, 0, stream>>>(xg, wp0_w, wp0_b, bigA, nullptr);
    k_conv3x3<16, 16, 2, 0><<<dim3(12, 12, NB), cb, 0, stream>>>(bigA, wp1_w, wp1_b, bigB, nullptr);
    k_final<<<(NB * HWS + 255) / 256, 256, 0, stream>>>(x, e3, bigB, wp2_w, wp2_b, coef, convadj_b, out, NB, 0);
  } else {
    for (int b = 0; b < NB; b++) {
      k_conv3x3<3, 16, 2, 0><<<dim3(12, 12, 1), cb, 0, stream>>>(xg + (size_t)b * 3 * HWS, wp0_w, wp0_b, bigA, nullptr);
      k_conv3x3<16, 16, 2, 0><<<dim3(12, 12, 1), cb, 0, stream>>>(bigA, wp1_w, wp1_b, bigB, nullptr);
      k_final<<<(HWS + 255) / 256, 256, 0, stream>>>(x, e3, bigB, wp2_w, wp2_b, coef, convadj_b, out, 1, b);
    }
  }
}